// Round 15
// baseline (1033.971 us; speedup 1.0000x reference)
//
#include <hip/hip_runtime.h>
#include <hip/hip_bf16.h>
#include <math.h>

#define NPIX 196608
#define SCALE_Q 0.17677669529663687f
#define LDA 136   // [128][128] bf16 tiles, padded (row stride 272B)
#define LDX 72    // [128][64] bf16 x-stage
#define LDV 20    // vt [32 d][16 tok]
#define LDO 68    // [128][64] f32 out staging (row stride 272B, same as LDA bf16)

typedef __attribute__((ext_vector_type(4))) float f32x4;
typedef __attribute__((ext_vector_type(8))) short short8;
typedef __attribute__((ext_vector_type(4))) short short4v;
typedef __hip_bfloat16 bf16;

__device__ __forceinline__ float gelu_f(float x) {
    float yy = 1.5957691216057308f * (x + 0.044715f * x * x * x);
    float e = __expf(yy);
    return x - x * __builtin_amdgcn_rcpf(e + 1.0f);
}
__device__ __forceinline__ float gelu_fast(float x) {
    float e = __expf(-1.702f * x);
    return x * __builtin_amdgcn_rcpf(1.0f + e);
}
__device__ __forceinline__ short bfbits(float f) {
    bf16 h = __float2bfloat16(f);
    return *reinterpret_cast<short*>(&h);
}
__device__ __forceinline__ float b2f(short s) {
    unsigned int u = ((unsigned int)(unsigned short)s) << 16;
    union { unsigned int u; float f; } c; c.u = u; return c.f;
}
__device__ __forceinline__ short8 gld8(const bf16* p) {
    return *reinterpret_cast<const short8*>(p);
}
__device__ __forceinline__ void bar_lds() {
    asm volatile("s_waitcnt lgkmcnt(0)" ::: "memory");
    __builtin_amdgcn_s_barrier();
}

// ---------------- weight convert (transposed bf16 images, linear) --------
__global__ __launch_bounds__(256) void k_convert(
    const float* __restrict__ wff1, const float* __restrict__ wqkv,
    const float* __restrict__ wproj, const float* __restrict__ wmlp1,
    const float* __restrict__ wmlp2, const float* __restrict__ wff2,
    bf16* __restrict__ dst)
{
    int gid = blockIdx.x * 256 + threadIdx.x;
    if (gid < 8192) {                       // ff1t [128 n][64 k]
        int n = gid >> 6, k = gid & 63;
        dst[gid] = __float2bfloat16(wff1[k * 128 + n]);
    } else if (gid < 106496) {              // qkvt [l][384 n][128 k]
        int r = gid - 8192; int l = r / 49152; r -= l * 49152;
        int n = r >> 7, k = r & 127;
        dst[gid] = __float2bfloat16(wqkv[l * 49152 + k * 384 + n]);
    } else if (gid < 139264) {              // projt [l][128 n][128 k]
        int r = gid - 106496; int l = r / 16384; r -= l * 16384;
        int n = r >> 7, k = r & 127;
        dst[gid] = __float2bfloat16(wproj[l * 16384 + k * 128 + n]);
    } else if (gid < 270336) {              // mlp1t [l][512 n][128 k]
        int r = gid - 139264; int l = r >> 16; r &= 65535;
        int n = r >> 7, k = r & 127;
        dst[gid] = __float2bfloat16(wmlp1[l * 65536 + k * 512 + n]);
    } else if (gid < 401408) {              // mlp2t [l][128 n][512 k]
        int r = gid - 270336; int l = r >> 16; r &= 65535;
        int n = r >> 9, k = r & 511;
        dst[gid] = __float2bfloat16(wmlp2[l * 65536 + k * 128 + n]);
    } else if (gid < 409600) {              // ff2t [64 n][128 k]
        int r = gid - 401408;
        int n = r >> 7, k = r & 127;
        dst[gid] = __float2bfloat16(wff2[k * 64 + n]);
    }
}

// ---------------- fused block: 128 tokens, 8 waves ------------------------
// Post-attention: wave = its 16-token window; all LDS traffic wave-local.
template <int OFFSET, int MODE>
__global__ __launch_bounds__(512, 2) void k_block(
    const float* __restrict__ x, bf16* __restrict__ h,
    const bf16* __restrict__ wf1t, const float* __restrict__ bf1,
    const float* __restrict__ g1, const float* __restrict__ be1,
    const bf16* __restrict__ wqt, const float* __restrict__ bq,
    const bf16* __restrict__ wpt, const float* __restrict__ bp,
    const float* __restrict__ g2, const float* __restrict__ be2,
    const bf16* __restrict__ w1t, const float* __restrict__ b1,
    const bf16* __restrict__ w2t, const float* __restrict__ b2,
    const bf16* __restrict__ wf2t, const float* __restrict__ bf2,
    float* __restrict__ out)
{
    __shared__ __align__(16) bf16 bufA[128 * LDA]; // stage(M1)/xn1 -> q/attnout -> u -> hstage/ob
    __shared__ __align__(16) bf16 bufB[128 * LDA]; // xstage(M0) -> k -> xn2 -> hfinal(M1)
    __shared__ __align__(16) bf16 bufC[5120];      // vt: 8 waves x 640
    const int tid = threadIdx.x, base = blockIdx.x * 128;
    const int wid = tid >> 6, lane = tid & 63;
    const int lrow = lane & 15, lgrp = lane >> 4;
    const int wtok = wid * 16;                 // wave's window base (block-local)
    const int hc = (wid & 3) * 32;             // attention head col base
    const int ts0 = (wid >> 2) * 4;            // attention tok-tile base
    const int myrow = wtok + lrow;             // lane's token row (block-local)
    int gtok = base + OFFSET + myrow; if (gtok >= NPIX) gtok -= NPIX;

    f32x4 hraw[8];   // lane: tok=myrow, value[nt][i] = X[n=nt*16+lgrp*4+i][tok]

    if (MODE == 0) {
        {   // stage x -> bufB [128][LDX]
            int row = tid >> 2, q = tid & 3;
#pragma unroll
            for (int s = 0; s < 2; ++s) {
                int gg = q + s * 4;
                const float4* src = reinterpret_cast<const float4*>(x + (size_t)(base + row) * 64 + gg * 8);
                float4 v0 = src[0], v1 = src[1];
                short8 w;
                w[0] = bfbits(v0.x); w[1] = bfbits(v0.y); w[2] = bfbits(v0.z); w[3] = bfbits(v0.w);
                w[4] = bfbits(v1.x); w[5] = bfbits(v1.y); w[6] = bfbits(v1.z); w[7] = bfbits(v1.w);
                *reinterpret_cast<short8*>(&bufB[row * LDX + gg * 8]) = w;
            }
        }
        bar_lds();                                   // b1: x-stage visible
        short8 xs[2];
#pragma unroll
        for (int kk = 0; kk < 2; ++kk)
            xs[kk] = *reinterpret_cast<const short8*>(&bufB[myrow * LDX + kk * 32 + lgrp * 8]);
        // ff1: D[n][tok] over 8 n-tiles
#pragma unroll
        for (int nt = 0; nt < 8; ++nt) {
            short8 wf[2];
#pragma unroll
            for (int kk = 0; kk < 2; ++kk)
                wf[kk] = gld8(wf1t + (size_t)(nt * 16 + lrow) * 64 + kk * 32 + lgrp * 8);
            f32x4 d = {0.f, 0.f, 0.f, 0.f};
#pragma unroll
            for (int kk = 0; kk < 2; ++kk)
                d = __builtin_amdgcn_mfma_f32_16x16x32_bf16(wf[kk], xs[kk], d, 0, 0, 0);
            float4 bv = *reinterpret_cast<const float4*>(bf1 + nt * 16 + lgrp * 4);
            f32x4 r;
            r[0] = gelu_f(d[0] + bv.x); r[1] = gelu_f(d[1] + bv.y);
            r[2] = gelu_f(d[2] + bv.z); r[3] = gelu_f(d[3] + bv.w);
            hraw[nt] = r;
        }
    } else {
        // coalesced h read -> bufA
#pragma unroll
        for (int it = 0; it < 4; ++it) {
            int i = it * 512 + tid;
            int row = i >> 4, ch = i & 15;
            int tok = base + OFFSET + row; if (tok >= NPIX) tok -= NPIX;
            short8 v = *reinterpret_cast<const short8*>(h + (size_t)tok * 128 + ch * 8);
            *reinterpret_cast<short8*>(&bufA[row * LDA + ch * 8]) = v;
        }
        bar_lds();                                   // b1: h-stage visible
#pragma unroll
        for (int nt = 0; nt < 8; ++nt) {
            short4v pk = *reinterpret_cast<const short4v*>(
                &bufA[myrow * LDA + nt * 16 + lgrp * 4]);
            f32x4 r;
            r[0] = b2f(pk[0]); r[1] = b2f(pk[1]); r[2] = b2f(pk[2]); r[3] = b2f(pk[3]);
            hraw[nt] = r;
        }
    }

    // ---- LN1 (lane-local token) -> xn1 in bufA (own rows)
    {
        float s = 0.f, q = 0.f;
#pragma unroll
        for (int nt = 0; nt < 8; ++nt)
#pragma unroll
            for (int i = 0; i < 4; ++i) { float v = hraw[nt][i]; s += v; q += v * v; }
        s += __shfl_xor(s, 16, 64); s += __shfl_xor(s, 32, 64);
        q += __shfl_xor(q, 16, 64); q += __shfl_xor(q, 32, 64);
        float mu = s * (1.f / 128.f);
        float rstd = rsqrtf(q * (1.f / 128.f) - mu * mu + 1e-5f);
#pragma unroll
        for (int nt = 0; nt < 8; ++nt) {
            float4 gv  = *reinterpret_cast<const float4*>(g1 + nt * 16 + lgrp * 4);
            float4 bev = *reinterpret_cast<const float4*>(be1 + nt * 16 + lgrp * 4);
            short4v pk;
            pk[0] = bfbits((hraw[nt][0] - mu) * rstd * gv.x + bev.x);
            pk[1] = bfbits((hraw[nt][1] - mu) * rstd * gv.y + bev.y);
            pk[2] = bfbits((hraw[nt][2] - mu) * rstd * gv.z + bev.z);
            pk[3] = bfbits((hraw[nt][3] - mu) * rstd * gv.w + bev.w);
            *reinterpret_cast<short4v*>(&bufA[myrow * LDA + nt * 16 + lgrp * 4]) = pk;
        }
    }
    bar_lds();                                       // b2: xn1 visible to all

    // ---- hoist xn1 B-frags for this wave's 4 attention tok-tiles
    short8 xb[4][4];
#pragma unroll
    for (int t = 0; t < 4; ++t)
#pragma unroll
        for (int kk = 0; kk < 4; ++kk)
            xb[t][kk] = *reinterpret_cast<const short8*>(
                &bufA[((ts0 + t) * 16 + lrow) * LDA + kk * 32 + lgrp * 8]);
    bar_lds();                                       // b3: hoists done, bufA writable

    // ======== attention: wave = head (wid&3) x 4 tok-tiles ========
#pragma unroll
    for (int qt = 0; qt < 2; ++qt) {                 // q -> bufA
        const int cb = hc + qt * 16;
        float4 bqv = *reinterpret_cast<const float4*>(bq + cb + lgrp * 4);
        short8 wf[4];
#pragma unroll
        for (int kk = 0; kk < 4; ++kk)
            wf[kk] = gld8(wqt + (size_t)(cb + lrow) * 128 + kk * 32 + lgrp * 8);
#pragma unroll
        for (int t = 0; t < 4; ++t) {
            f32x4 d = {0.f, 0.f, 0.f, 0.f};
#pragma unroll
            for (int kk = 0; kk < 4; ++kk)
                d = __builtin_amdgcn_mfma_f32_16x16x32_bf16(wf[kk], xb[t][kk], d, 0, 0, 0);
            short4v pk;
            pk[0] = bfbits((d[0] + bqv.x) * SCALE_Q); pk[1] = bfbits((d[1] + bqv.y) * SCALE_Q);
            pk[2] = bfbits((d[2] + bqv.z) * SCALE_Q); pk[3] = bfbits((d[3] + bqv.w) * SCALE_Q);
            *reinterpret_cast<short4v*>(
                &bufA[((ts0 + t) * 16 + lrow) * LDA + cb + lgrp * 4]) = pk;
        }
    }
#pragma unroll
    for (int kt = 0; kt < 2; ++kt) {                 // k -> bufB
        const int cb = hc + kt * 16;
        float4 bqv = *reinterpret_cast<const float4*>(bq + 128 + cb + lgrp * 4);
        short8 wf[4];
#pragma unroll
        for (int kk = 0; kk < 4; ++kk)
            wf[kk] = gld8(wqt + (size_t)(128 + cb + lrow) * 128 + kk * 32 + lgrp * 8);
#pragma unroll
        for (int t = 0; t < 4; ++t) {
            f32x4 d = {0.f, 0.f, 0.f, 0.f};
#pragma unroll
            for (int kk = 0; kk < 4; ++kk)
                d = __builtin_amdgcn_mfma_f32_16x16x32_bf16(wf[kk], xb[t][kk], d, 0, 0, 0);
            short4v pk;
            pk[0] = bfbits(d[0] + bqv.x); pk[1] = bfbits(d[1] + bqv.y);
            pk[2] = bfbits(d[2] + bqv.z); pk[3] = bfbits(d[3] + bqv.w);
            *reinterpret_cast<short4v*>(
                &bufB[((ts0 + t) * 16 + lrow) * LDA + cb + lgrp * 4]) = pk;
        }
    }
    bf16* vt = bufC + wid * 640;
#pragma unroll
    for (int t = 0; t < 4; ++t) {                    // per tile: v -> scores -> PV
#pragma unroll
        for (int vt_ = 0; vt_ < 2; ++vt_) {
            const int cb = hc + vt_ * 16;
            float4 bqv = *reinterpret_cast<const float4*>(bq + 256 + cb + lgrp * 4);
            short8 wf[4];
#pragma unroll
            for (int kk = 0; kk < 4; ++kk)
                wf[kk] = gld8(wqt + (size_t)(256 + cb + lrow) * 128 + kk * 32 + lgrp * 8);
            f32x4 d = {0.f, 0.f, 0.f, 0.f};
#pragma unroll
            for (int kk = 0; kk < 4; ++kk)
                d = __builtin_amdgcn_mfma_f32_16x16x32_bf16(wf[kk], xb[t][kk], d, 0, 0, 0);
#pragma unroll
            for (int i = 0; i < 4; ++i) {
                int dd = vt_ * 16 + lgrp * 4 + i;
                vt[dd * LDV + lrow] = __float2bfloat16(d[i] + ((const float*)&bqv)[i]);
            }
        }
        const int row = (ts0 + t) * 16 + lrow;
        short8 aq = *reinterpret_cast<const short8*>(&bufA[row * LDA + hc + lgrp * 8]);
        short8 bk = *reinterpret_cast<const short8*>(&bufB[row * LDA + hc + lgrp * 8]);
        f32x4 z = {0.f, 0.f, 0.f, 0.f};
        f32x4 s = __builtin_amdgcn_mfma_f32_16x16x32_bf16(bk, aq, z, 0, 0, 0);
        float m_ = fmaxf(fmaxf(s[0], s[1]), fmaxf(s[2], s[3]));
        m_ = fmaxf(m_, __shfl_xor(m_, 16, 64));
        m_ = fmaxf(m_, __shfl_xor(m_, 32, 64));
        float e0 = __expf(s[0] - m_), e1 = __expf(s[1] - m_);
        float e2 = __expf(s[2] - m_), e3 = __expf(s[3] - m_);
        float sum = e0 + e1 + e2 + e3;
        sum += __shfl_xor(sum, 16, 64);
        sum += __shfl_xor(sum, 32, 64);
        float rr = __builtin_amdgcn_rcpf(sum);
        short4v pp;
        pp[0] = bfbits(e0 * rr); pp[1] = bfbits(e1 * rr);
        pp[2] = bfbits(e2 * rr); pp[3] = bfbits(e3 * rr);
        *reinterpret_cast<short4v*>(&bufA[row * LDA + hc + lgrp * 4]) = pp;

        short8 z8 = {0, 0, 0, 0, 0, 0, 0, 0};
        short8 bp_ = z8;
        if (lgrp < 2)
            bp_ = *reinterpret_cast<const short8*>(&bufA[row * LDA + hc + lgrp * 8]);
#pragma unroll
        for (int dt = 0; dt < 2; ++dt) {
            short8 av = z8;
            if (lgrp < 2)
                av = *reinterpret_cast<const short8*>(&vt[(dt * 16 + lrow) * LDV + lgrp * 8]);
            f32x4 o = __builtin_amdgcn_mfma_f32_16x16x32_bf16(av, bp_, z, 0, 0, 0);
            short4v pk;
            pk[0] = bfbits(o[0]); pk[1] = bfbits(o[1]); pk[2] = bfbits(o[2]); pk[3] = bfbits(o[3]);
            *reinterpret_cast<short4v*>(&bufA[row * LDA + hc + dt * 16 + lgrp * 4]) = pk;
        }
    }
    bar_lds();                                       // b4: attn-out visible

    // ======== tok-split tail: wave = its window; zero barriers ========
    // proj + residual
    short8 af[4];
#pragma unroll
    for (int kk = 0; kk < 4; ++kk)
        af[kk] = *reinterpret_cast<const short8*>(
            &bufA[myrow * LDA + kk * 32 + lgrp * 8]);
    f32x4 hres[8];
#pragma unroll
    for (int nt = 0; nt < 8; ++nt) {
        short8 wf[4];
#pragma unroll
        for (int kk = 0; kk < 4; ++kk)
            wf[kk] = gld8(wpt + (size_t)(nt * 16 + lrow) * 128 + kk * 32 + lgrp * 8);
        f32x4 d = {0.f, 0.f, 0.f, 0.f};
#pragma unroll
        for (int kk = 0; kk < 4; ++kk)
            d = __builtin_amdgcn_mfma_f32_16x16x32_bf16(wf[kk], af[kk], d, 0, 0, 0);
        float4 bpv = *reinterpret_cast<const float4*>(bp + nt * 16 + lgrp * 4);
        f32x4 r = hraw[nt];
        r[0] += bpv.x + d[0]; r[1] += bpv.y + d[1];
        r[2] += bpv.z + d[2]; r[3] += bpv.w + d[3];
        hres[nt] = r;
    }

    // LN2 (lane-local) -> xn2 to bufB own rows
    {
        float s = 0.f, q = 0.f;
#pragma unroll
        for (int nt = 0; nt < 8; ++nt)
#pragma unroll
            for (int i = 0; i < 4; ++i) { float v = hres[nt][i]; s += v; q += v * v; }
        s += __shfl_xor(s, 16, 64); s += __shfl_xor(s, 32, 64);
        q += __shfl_xor(q, 16, 64); q += __shfl_xor(q, 32, 64);
        float mu = s * (1.f / 128.f);
        float rstd = rsqrtf(q * (1.f / 128.f) - mu * mu + 1e-5f);
#pragma unroll
        for (int nt = 0; nt < 8; ++nt) {
            float4 gv  = *reinterpret_cast<const float4*>(g2 + nt * 16 + lgrp * 4);
            float4 bev = *reinterpret_cast<const float4*>(be2 + nt * 16 + lgrp * 4);
            short4v pk;
            pk[0] = bfbits((hres[nt][0] - mu) * rstd * gv.x + bev.x);
            pk[1] = bfbits((hres[nt][1] - mu) * rstd * gv.y + bev.y);
            pk[2] = bfbits((hres[nt][2] - mu) * rstd * gv.z + bev.z);
            pk[3] = bfbits((hres[nt][3] - mu) * rstd * gv.w + bev.w);
            *reinterpret_cast<short4v*>(&bufB[myrow * LDA + nt * 16 + lgrp * 4]) = pk;
        }
    }
    short8 xf[4];
#pragma unroll
    for (int kk = 0; kk < 4; ++kk)
        xf[kk] = *reinterpret_cast<const short8*>(
            &bufB[myrow * LDA + kk * 32 + lgrp * 8]);

    // MLP: 4 chunks; u bounced through bufA own rows (wave-local)
    f32x4 acc2[8];
#pragma unroll
    for (int nt = 0; nt < 8; ++nt) acc2[nt] = (f32x4){0.f, 0.f, 0.f, 0.f};
#pragma unroll
    for (int ch = 0; ch < 4; ++ch) {
#pragma unroll
        for (int un = 0; un < 8; ++un) {
            short8 wf[4];
#pragma unroll
            for (int kk = 0; kk < 4; ++kk)
                wf[kk] = gld8(w1t + (size_t)(ch * 128 + un * 16 + lrow) * 128 + kk * 32 + lgrp * 8);
            f32x4 d = {0.f, 0.f, 0.f, 0.f};
#pragma unroll
            for (int kk = 0; kk < 4; ++kk)
                d = __builtin_amdgcn_mfma_f32_16x16x32_bf16(wf[kk], xf[kk], d, 0, 0, 0);
            float4 bv = *reinterpret_cast<const float4*>(b1 + ch * 128 + un * 16 + lgrp * 4);
            short4v pk;
            pk[0] = bfbits(gelu_fast(d[0] + bv.x)); pk[1] = bfbits(gelu_fast(d[1] + bv.y));
            pk[2] = bfbits(gelu_fast(d[2] + bv.z)); pk[3] = bfbits(gelu_fast(d[3] + bv.w));
            *reinterpret_cast<short4v*>(&bufA[myrow * LDA + un * 16 + lgrp * 4]) = pk;
        }
        short8 uf[4];
#pragma unroll
        for (int kk = 0; kk < 4; ++kk)
            uf[kk] = *reinterpret_cast<const short8*>(
                &bufA[myrow * LDA + kk * 32 + lgrp * 8]);
        __builtin_amdgcn_s_setprio(1);
#pragma unroll
        for (int nt = 0; nt < 8; ++nt) {
            short8 wf[4];
#pragma unroll
            for (int kk = 0; kk < 4; ++kk)
                wf[kk] = gld8(w2t + (size_t)(nt * 16 + lrow) * 512 + ch * 128 + kk * 32 + lgrp * 8);
#pragma unroll
            for (int kk = 0; kk < 4; ++kk)
                acc2[nt] = __builtin_amdgcn_mfma_f32_16x16x32_bf16(wf[kk], uf[kk], acc2[nt], 0, 0, 0);
        }
        __builtin_amdgcn_s_setprio(0);
    }

    if (MODE == 0) {
        // hfinal (bf16) -> bufA own rows -> coalesced write
#pragma unroll
        for (int nt = 0; nt < 8; ++nt) {
            float4 b2v = *reinterpret_cast<const float4*>(b2 + nt * 16 + lgrp * 4);
            short4v pk;
            pk[0] = bfbits(hres[nt][0] + b2v.x + acc2[nt][0]);
            pk[1] = bfbits(hres[nt][1] + b2v.y + acc2[nt][1]);
            pk[2] = bfbits(hres[nt][2] + b2v.z + acc2[nt][2]);
            pk[3] = bfbits(hres[nt][3] + b2v.w + acc2[nt][3]);
            *reinterpret_cast<short4v*>(&bufA[myrow * LDA + nt * 16 + lgrp * 4]) = pk;
        }
        bar_lds();                                   // b5: stage visible
#pragma unroll
        for (int it = 0; it < 4; ++it) {
            int i = it * 512 + tid;
            int row = i >> 4, ch = i & 15;
            short8 v = *reinterpret_cast<const short8*>(&bufA[row * LDA + ch * 8]);
            *reinterpret_cast<short8*>(h + (size_t)(base + row) * 128 + ch * 8) = v;
        }
    } else {
        // hfinal -> bufB own rows; ff2; out (f32) -> bufA; coalesced +x
#pragma unroll
        for (int nt = 0; nt < 8; ++nt) {
            float4 b2v = *reinterpret_cast<const float4*>(b2 + nt * 16 + lgrp * 4);
            short4v pk;
            pk[0] = bfbits(hres[nt][0] + b2v.x + acc2[nt][0]);
            pk[1] = bfbits(hres[nt][1] + b2v.y + acc2[nt][1]);
            pk[2] = bfbits(hres[nt][2] + b2v.z + acc2[nt][2]);
            pk[3] = bfbits(hres[nt][3] + b2v.w + acc2[nt][3]);
            *reinterpret_cast<short4v*>(&bufB[myrow * LDA + nt * 16 + lgrp * 4]) = pk;
        }
        short8 hf[4];
#pragma unroll
        for (int kk = 0; kk < 4; ++kk)
            hf[kk] = *reinterpret_cast<const short8*>(
                &bufB[myrow * LDA + kk * 32 + lgrp * 8]);
        float* ob = reinterpret_cast<float*>(bufA);
#pragma unroll
        for (int nt = 0; nt < 4; ++nt) {
            short8 wf[4];
#pragma unroll
            for (int kk = 0; kk < 4; ++kk)
                wf[kk] = gld8(wf2t + (size_t)(nt * 16 + lrow) * 128 + kk * 32 + lgrp * 8);
            f32x4 d = {0.f, 0.f, 0.f, 0.f};
#pragma unroll
            for (int kk = 0; kk < 4; ++kk)
                d = __builtin_amdgcn_mfma_f32_16x16x32_bf16(wf[kk], hf[kk], d, 0, 0, 0);
            float4 bv = *reinterpret_cast<const float4*>(bf2 + nt * 16 + lgrp * 4);
            float4 sv;
            sv.x = bv.x + d[0]; sv.y = bv.y + d[1];
            sv.z = bv.z + d[2]; sv.w = bv.w + d[3];
            *reinterpret_cast<float4*>(&ob[myrow * LDO + nt * 16 + lgrp * 4]) = sv;
        }
        bar_lds();                                   // b5: stage visible
#pragma unroll
        for (int it = 0; it < 4; ++it) {
            int i = it * 512 + tid;
            int row = i >> 4, ch = i & 15;
            int tok = base + OFFSET + row; if (tok >= NPIX) tok -= NPIX;
            float4 sv = *reinterpret_cast<const float4*>(&ob[row * LDO + ch * 4]);
            float4 xv = *reinterpret_cast<const float4*>(x + (size_t)tok * 64 + ch * 4);
            float4 ov;
            ov.x = xv.x + sv.x; ov.y = xv.y + sv.y;
            ov.z = xv.z + sv.z; ov.w = xv.w + sv.w;
            *reinterpret_cast<float4*>(out + (size_t)tok * 64 + ch * 4) = ov;
        }
    }
}

extern "C" void kernel_launch(void* const* d_in, const int* in_sizes, int n_in,
                              void* d_out, int out_size, void* d_ws, size_t ws_size,
                              hipStream_t stream) {
    (void)in_sizes; (void)n_in; (void)out_size; (void)ws_size;
    const float* x      = (const float*)d_in[0];
    const float* w_ff1  = (const float*)d_in[1];
    const float* b_ff1  = (const float*)d_in[2];
    const float* ln1_g  = (const float*)d_in[3];
    const float* ln1_b  = (const float*)d_in[4];
    const float* w_qkv  = (const float*)d_in[5];
    const float* b_qkv  = (const float*)d_in[6];
    const float* w_proj = (const float*)d_in[7];
    const float* b_proj = (const float*)d_in[8];
    const float* ln2_g  = (const float*)d_in[9];
    const float* ln2_b  = (const float*)d_in[10];
    const float* w_mlp1 = (const float*)d_in[11];
    const float* b_mlp1 = (const float*)d_in[12];
    const float* w_mlp2 = (const float*)d_in[13];
    const float* b_mlp2 = (const float*)d_in[14];
    const float* w_ff2  = (const float*)d_in[15];
    const float* b_ff2  = (const float*)d_in[16];
    float* out = (float*)d_out;

    bf16* h = (bf16*)d_ws;                                     // [NPIX,128] bf16
    bf16* wbf = (bf16*)((char*)d_ws + (size_t)NPIX * 128 * 2);
    bf16* ff1t  = wbf;            // [128][64]
    bf16* qkvt  = wbf + 8192;     // 2x[384][128]
    bf16* projt = wbf + 106496;   // 2x[128][128]
    bf16* mlp1t = wbf + 139264;   // 2x[512][128]
    bf16* mlp2t = wbf + 270336;   // 2x[128][512]
    bf16* ff2t  = wbf + 401408;   // [64][128]

    k_convert<<<1600, dim3(256), 0, stream>>>(w_ff1, w_qkv, w_proj, w_mlp1, w_mlp2, w_ff2, wbf);

    const int NB = NPIX / 128;  // 1536
    k_block<0, 0><<<NB, dim3(512), 0, stream>>>(x, h,
        ff1t, b_ff1,
        ln1_g, ln1_b, qkvt, b_qkv, projt, b_proj,
        ln2_g, ln2_b, mlp1t, b_mlp1, mlp2t, b_mlp2,
        ff2t, b_ff2, out);

    k_block<8, 1><<<NB, dim3(512), 0, stream>>>(x, h,
        ff1t, b_ff1,
        ln1_g + 128, ln1_b + 128, qkvt + 49152, b_qkv + 384, projt + 16384, b_proj + 128,
        ln2_g + 128, ln2_b + 128, mlp1t + 65536, b_mlp1 + 512, mlp2t + 65536, b_mlp2 + 128,
        ff2t, b_ff2, out);
}

// Round 16
// 407.919 us; speedup vs baseline: 2.5347x; 2.5347x over previous
//
#include <hip/hip_runtime.h>
#include <hip/hip_bf16.h>
#include <math.h>

#define NPIX 196608
#define SCALE_Q 0.17677669529663687f

typedef __attribute__((ext_vector_type(4))) float f32x4;
typedef __attribute__((ext_vector_type(8))) short short8;
typedef __attribute__((ext_vector_type(4))) short short4v;
typedef __hip_bfloat16 bf16;

__device__ __forceinline__ float gelu_f(float x) {          // accurate (ff1)
    float yy = 1.5957691216057308f * (x + 0.044715f * x * x * x);
    float e = __expf(yy);
    return x - x * __builtin_amdgcn_rcpf(e + 1.0f);
}
__device__ __forceinline__ float gelu_fast(float x) {       // sigmoid form (mlp1)
    float e = __expf(-1.702f * x);
    return x * __builtin_amdgcn_rcpf(1.0f + e);
}

__device__ __forceinline__ short bfbits(float f) {
    bf16 h = __float2bfloat16(f);
    return *reinterpret_cast<short*>(&h);
}

__device__ __forceinline__ short8 ldsA(const bf16* buf, int row, int el) {
    return *reinterpret_cast<const short8*>(buf + row * 128 + (el ^ ((row & 7) << 3)));
}
__device__ __forceinline__ short8 ldsA64(const bf16* buf, int row, int el) {
    return *reinterpret_cast<const short8*>(buf + row * 64 + (el ^ ((row & 7) << 3)));
}
__device__ __forceinline__ short8 gld8(const bf16* p) {
    return *reinterpret_cast<const short8*>(p);
}

// LDS-only barrier (no vmcnt drain, no sched pinning — m141 lesson)
__device__ __forceinline__ void bar_lds() {
    asm volatile("s_waitcnt lgkmcnt(0)" ::: "memory");
    __builtin_amdgcn_s_barrier();
}

// ---------------- weight convert to bf16 transposed images (all linear) ---
__global__ __launch_bounds__(256) void k_convert(
    const float* __restrict__ wff1, const float* __restrict__ wqkv,
    const float* __restrict__ wproj, const float* __restrict__ wmlp1,
    const float* __restrict__ wmlp2, const float* __restrict__ wff2,
    bf16* __restrict__ dst)
{
    int gid = blockIdx.x * 256 + threadIdx.x;
    if (gid < 8192) {                       // ff1t [128 n][64 k]
        int n = gid >> 6, k = gid & 63;
        dst[gid] = __float2bfloat16(wff1[k * 128 + n]);
    } else if (gid < 106496) {              // qkvt [l][384 n][128 k]
        int r = gid - 8192; int l = r / 49152; r -= l * 49152;
        int n = r >> 7, k = r & 127;
        dst[gid] = __float2bfloat16(wqkv[l * 49152 + k * 384 + n]);
    } else if (gid < 139264) {              // projt [l][128 n][128 k]
        int r = gid - 106496; int l = r / 16384; r -= l * 16384;
        int n = r >> 7, k = r & 127;
        dst[gid] = __float2bfloat16(wproj[l * 16384 + k * 128 + n]);
    } else if (gid < 270336) {              // mlp1t [l][512 n][128 k]
        int r = gid - 139264; int l = r >> 16; r &= 65535;
        int n = r >> 7, k = r & 127;
        dst[gid] = __float2bfloat16(wmlp1[l * 65536 + k * 512 + n]);
    } else if (gid < 401408) {              // mlp2t [l][128 n][512 k]
        int r = gid - 270336; int l = r >> 16; r &= 65535;
        int n = r >> 9, k = r & 511;
        dst[gid] = __float2bfloat16(wmlp2[l * 65536 + k * 128 + n]);
    } else if (gid < 409600) {              // ff2t [64 n][128 k]
        int r = gid - 401408;
        int n = r >> 7, k = r & 127;
        dst[gid] = __float2bfloat16(wff2[k * 64 + n]);
    }
}

// ---------------- fused block kernel ------------------------------------
// MODE 0: ff1 fused at head (reads x), writes h at tail.
// MODE 1: reads h at head, ff2 fused at tail (writes out).
template <int OFFSET, int MODE>
__global__ __launch_bounds__(256, 3) void k_block(
    const float* __restrict__ x, float* __restrict__ h,
    const bf16* __restrict__ wf1t, const float* __restrict__ bf1,
    const float* __restrict__ g1, const float* __restrict__ be1,
    const bf16* __restrict__ wqt, const float* __restrict__ bq,
    const bf16* __restrict__ wpt, const float* __restrict__ bp,
    const float* __restrict__ g2, const float* __restrict__ be2,
    const bf16* __restrict__ w1t, const float* __restrict__ b1,
    const bf16* __restrict__ w2t, const float* __restrict__ b2,
    const bf16* __restrict__ wf2t, const float* __restrict__ bf2,
    float* __restrict__ out)
{
    __shared__ bf16 bufA[8192];   // xn1 -> q/P/attn-out -> u(even)
    __shared__ bf16 bufB[8192];   // k -> xn2 -> hfinal(M1)
    __shared__ bf16 bufC[8192];   // xs(M0)/LN partials -> vt -> u(odd)
    const int tid = threadIdx.x, base = blockIdx.x * 64;
    const int wid = tid >> 6, lrow = tid & 15, lgrp = (tid >> 4) & 3;
    const int cb0 = wid * 32;                  // wave's n-slice (proj/mlp split)
    const int hc  = wid * 32;                  // wave's head col base (attention)

    f32x4 hraw[2][4];   // [nt][tt]: n = cb0+nt*16+lgrp*4+i, token tt*16+lrow

    if (MODE == 0) {
        short8 wf1[2][2];
#pragma unroll
        for (int nt = 0; nt < 2; ++nt)
#pragma unroll
            for (int kk = 0; kk < 2; ++kk)
                wf1[nt][kk] = gld8(wf1t + (size_t)(cb0 + nt * 16 + lrow) * 64 + kk * 32 + lgrp * 8);
        {
            int row = tid >> 2, q = tid & 3;
#pragma unroll
            for (int s = 0; s < 2; ++s) {
                int gg = q + s * 4;
                const float4* src = reinterpret_cast<const float4*>(x + (size_t)(base + row) * 64 + gg * 8);
                float4 v0 = src[0], v1 = src[1];
                short8 w;
                w[0] = bfbits(v0.x); w[1] = bfbits(v0.y); w[2] = bfbits(v0.z); w[3] = bfbits(v0.w);
                w[4] = bfbits(v1.x); w[5] = bfbits(v1.y); w[6] = bfbits(v1.z); w[7] = bfbits(v1.w);
                *reinterpret_cast<short8*>(&bufC[row * 64 + ((gg * 8) ^ ((row & 7) << 3))]) = w;
            }
        }
        bar_lds();
        short8 xb1[4][2];
#pragma unroll
        for (int tt = 0; tt < 4; ++tt)
#pragma unroll
            for (int kk = 0; kk < 2; ++kk)
                xb1[tt][kk] = ldsA64(bufC, tt * 16 + lrow, kk * 32 + lgrp * 8);
        bar_lds();   // xs reads done; bufC reusable
#pragma unroll
        for (int nt = 0; nt < 2; ++nt) {
            float4 bv = *reinterpret_cast<const float4*>(bf1 + cb0 + nt * 16 + lgrp * 4);
#pragma unroll
            for (int tt = 0; tt < 4; ++tt) {
                f32x4 d = {0.f, 0.f, 0.f, 0.f};
#pragma unroll
                for (int kk = 0; kk < 2; ++kk)
                    d = __builtin_amdgcn_mfma_f32_16x16x32_bf16(wf1[nt][kk], xb1[tt][kk], d, 0, 0, 0);
                f32x4 r;
                r[0] = gelu_f(d[0] + bv.x); r[1] = gelu_f(d[1] + bv.y);
                r[2] = gelu_f(d[2] + bv.z); r[3] = gelu_f(d[3] + bv.w);
                hraw[nt][tt] = r;
            }
        }
    } else {
#pragma unroll
        for (int nt = 0; nt < 2; ++nt)
#pragma unroll
            for (int tt = 0; tt < 4; ++tt) {
                int tok = base + OFFSET + tt * 16 + lrow; if (tok >= NPIX) tok -= NPIX;
                float4 hv = *reinterpret_cast<const float4*>(h + (size_t)tok * 128 + cb0 + nt * 16 + lgrp * 4);
                f32x4 r; r[0] = hv.x; r[1] = hv.y; r[2] = hv.z; r[3] = hv.w;
                hraw[nt][tt] = r;
            }
    }

    // ---- LN1 (cross-wave over n) -> xn1 in bufA
    float2* ws = reinterpret_cast<float2*>(bufC);
#pragma unroll
    for (int tt = 0; tt < 4; ++tt) {
        float s = 0.f, q = 0.f;
#pragma unroll
        for (int nt = 0; nt < 2; ++nt)
#pragma unroll
            for (int i = 0; i < 4; ++i) { float v = hraw[nt][tt][i]; s += v; q += v * v; }
        s += __shfl_xor(s, 16, 64); s += __shfl_xor(s, 32, 64);
        q += __shfl_xor(q, 16, 64); q += __shfl_xor(q, 32, 64);
        if (lgrp == 0) { float2 t2; t2.x = s; t2.y = q; ws[wid * 64 + tt * 16 + lrow] = t2; }
    }
    bar_lds();
    {
        float mu[4], rstd[4];
#pragma unroll
        for (int tt = 0; tt < 4; ++tt) {
            float s = 0.f, q = 0.f;
#pragma unroll
            for (int w = 0; w < 4; ++w) {
                float2 t2 = ws[w * 64 + tt * 16 + lrow];
                s += t2.x; q += t2.y;
            }
            float m = s * (1.f / 128.f);
            mu[tt] = m;
            rstd[tt] = rsqrtf(q * (1.f / 128.f) - m * m + 1e-5f);
        }
        float4 gv[2], bev[2];
#pragma unroll
        for (int nt = 0; nt < 2; ++nt) {
            gv[nt]  = *reinterpret_cast<const float4*>(g1 + cb0 + nt * 16 + lgrp * 4);
            bev[nt] = *reinterpret_cast<const float4*>(be1 + cb0 + nt * 16 + lgrp * 4);
        }
#pragma unroll
        for (int nt = 0; nt < 2; ++nt)
#pragma unroll
            for (int tt = 0; tt < 4; ++tt) {
                short4v pk;
                pk[0] = bfbits((hraw[nt][tt][0] - mu[tt]) * rstd[tt] * gv[nt].x + bev[nt].x);
                pk[1] = bfbits((hraw[nt][tt][1] - mu[tt]) * rstd[tt] * gv[nt].y + bev[nt].y);
                pk[2] = bfbits((hraw[nt][tt][2] - mu[tt]) * rstd[tt] * gv[nt].z + bev[nt].z);
                pk[3] = bfbits((hraw[nt][tt][3] - mu[tt]) * rstd[tt] * gv[nt].w + bev[nt].w);
                int row = tt * 16 + lrow;
                int c = cb0 + nt * 16 + lgrp * 4;
                *reinterpret_cast<short4v*>(&bufA[row * 128 + (c ^ ((row & 7) << 3))]) = pk;
            }
    }
    // long-distance prefetch: proj frags (consumed after attention)
    short8 wfp[2][4];
#pragma unroll
    for (int nt = 0; nt < 2; ++nt)
#pragma unroll
        for (int kk = 0; kk < 4; ++kk)
            wfp[nt][kk] = gld8(wpt + (size_t)(cb0 + nt * 16 + lrow) * 128 + kk * 32 + lgrp * 8);
    bar_lds();

    short8 xb[4][4];
#pragma unroll
    for (int tt = 0; tt < 4; ++tt)
#pragma unroll
        for (int kk = 0; kk < 4; ++kk)
            xb[tt][kk] = ldsA(bufA, tt * 16 + lrow, kk * 32 + lgrp * 8);
    bar_lds();   // xn1 reads done before q overwrites bufA

    // ======== per-head attention: wave w = head w, NO cross-wave barriers =====
#pragma unroll
    for (int qt = 0; qt < 2; ++qt) {
        const int cb = hc + qt * 16;
        float4 bqv = *reinterpret_cast<const float4*>(bq + cb + lgrp * 4);
        short8 wf[4];
#pragma unroll
        for (int kk = 0; kk < 4; ++kk)
            wf[kk] = gld8(wqt + (size_t)(cb + lrow) * 128 + kk * 32 + lgrp * 8);
#pragma unroll
        for (int tt = 0; tt < 4; ++tt) {
            f32x4 d = {0.f, 0.f, 0.f, 0.f};
#pragma unroll
            for (int kk = 0; kk < 4; ++kk)
                d = __builtin_amdgcn_mfma_f32_16x16x32_bf16(wf[kk], xb[tt][kk], d, 0, 0, 0);
            int row = tt * 16 + lrow;
            int c = cb + lgrp * 4;
            short4v pk;
            pk[0] = bfbits((d[0] + bqv.x) * SCALE_Q); pk[1] = bfbits((d[1] + bqv.y) * SCALE_Q);
            pk[2] = bfbits((d[2] + bqv.z) * SCALE_Q); pk[3] = bfbits((d[3] + bqv.w) * SCALE_Q);
            *reinterpret_cast<short4v*>(&bufA[row * 128 + (c ^ ((row & 7) << 3))]) = pk;
        }
    }
#pragma unroll
    for (int kt = 0; kt < 2; ++kt) {
        const int cb = hc + kt * 16;
        float4 bqv = *reinterpret_cast<const float4*>(bq + 128 + cb + lgrp * 4);
        short8 wf[4];
#pragma unroll
        for (int kk = 0; kk < 4; ++kk)
            wf[kk] = gld8(wqt + (size_t)(128 + cb + lrow) * 128 + kk * 32 + lgrp * 8);
#pragma unroll
        for (int tt = 0; tt < 4; ++tt) {
            f32x4 d = {0.f, 0.f, 0.f, 0.f};
#pragma unroll
            for (int kk = 0; kk < 4; ++kk)
                d = __builtin_amdgcn_mfma_f32_16x16x32_bf16(wf[kk], xb[tt][kk], d, 0, 0, 0);
            int row = tt * 16 + lrow;
            int c = cb + lgrp * 4;
            short4v pk;
            pk[0] = bfbits(d[0] + bqv.x); pk[1] = bfbits(d[1] + bqv.y);
            pk[2] = bfbits(d[2] + bqv.z); pk[3] = bfbits(d[3] + bqv.w);
            *reinterpret_cast<short4v*>(&bufB[row * 128 + (c ^ ((row & 7) << 3))]) = pk;
        }
    }
    // v tiles -> wave-private vt slice in bufC: vt[d 32][tok 64]
    bf16* vt = bufC + wid * 2048;
#pragma unroll
    for (int vt_ = 0; vt_ < 2; ++vt_) {
        const int cb = hc + vt_ * 16;
        float4 bqv = *reinterpret_cast<const float4*>(bq + 256 + cb + lgrp * 4);
        short8 wf[4];
#pragma unroll
        for (int kk = 0; kk < 4; ++kk)
            wf[kk] = gld8(wqt + (size_t)(256 + cb + lrow) * 128 + kk * 32 + lgrp * 8);
#pragma unroll
        for (int tt = 0; tt < 4; ++tt) {
            f32x4 d = {0.f, 0.f, 0.f, 0.f};
#pragma unroll
            for (int kk = 0; kk < 4; ++kk)
                d = __builtin_amdgcn_mfma_f32_16x16x32_bf16(wf[kk], xb[tt][kk], d, 0, 0, 0);
#pragma unroll
            for (int i = 0; i < 4; ++i)
                vt[(vt_ * 16 + lgrp * 4 + i) * 64 + tt * 16 + lrow] =
                    __float2bfloat16(d[i] + ((const float*)&bqv)[i]);
        }
    }

    // per-window: scores (swapped operands) -> softmax -> P -> PV (all wave-local)
#pragma unroll
    for (int tt = 0; tt < 4; ++tt) {
        const int row = tt * 16 + lrow;
        const int swr = (lrow & 7) << 3;
        short8 aq = *reinterpret_cast<const short8*>(&bufA[row * 128 + ((hc + lgrp * 8) ^ swr)]);
        short8 bk = *reinterpret_cast<const short8*>(&bufB[row * 128 + ((hc + lgrp * 8) ^ swr)]);
        f32x4 z = {0.f, 0.f, 0.f, 0.f};
        // D[tok_k][tok_q]: lane col = tok_q = lrow, rows tok_k = lgrp*4+i
        f32x4 s = __builtin_amdgcn_mfma_f32_16x16x32_bf16(bk, aq, z, 0, 0, 0);
        float m_ = fmaxf(fmaxf(s[0], s[1]), fmaxf(s[2], s[3]));
        m_ = fmaxf(m_, __shfl_xor(m_, 16, 64));
        m_ = fmaxf(m_, __shfl_xor(m_, 32, 64));
        float e0 = __expf(s[0] - m_), e1 = __expf(s[1] - m_);
        float e2 = __expf(s[2] - m_), e3 = __expf(s[3] - m_);
        float sum = e0 + e1 + e2 + e3;
        sum += __shfl_xor(sum, 16, 64);
        sum += __shfl_xor(sum, 32, 64);
        float r = __builtin_amdgcn_rcpf(sum);
        short4v pp;
        pp[0] = bfbits(e0 * r); pp[1] = bfbits(e1 * r);
        pp[2] = bfbits(e2 * r); pp[3] = bfbits(e3 * r);
        *reinterpret_cast<short4v*>(&bufA[row * 128 + ((hc + lgrp * 4) ^ swr)]) = pp;

        // PV: A = vt[d][key], B = P[key][q]; keys 16..31 zero (lgrp>=2)
        short8 z8 = {0, 0, 0, 0, 0, 0, 0, 0};
        short8 bp_ = z8;
        if (lgrp < 2)
            bp_ = *reinterpret_cast<const short8*>(&bufA[row * 128 + ((hc + lgrp * 8) ^ swr)]);
#pragma unroll
        for (int dt = 0; dt < 2; ++dt) {
            short8 av = z8;
            if (lgrp < 2)
                av = *reinterpret_cast<const short8*>(&vt[(dt * 16 + lrow) * 64 + tt * 16 + lgrp * 8]);
            f32x4 o = __builtin_amdgcn_mfma_f32_16x16x32_bf16(av, bp_, z, 0, 0, 0);
            short4v pk;
            pk[0] = bfbits(o[0]); pk[1] = bfbits(o[1]); pk[2] = bfbits(o[2]); pk[3] = bfbits(o[3]);
            *reinterpret_cast<short4v*>(&bufA[row * 128 + ((hc + dt * 16 + lgrp * 4) ^ swr)]) = pk;
        }
    }
    bar_lds();   // attn-out complete across waves

    // ---- proj + residual (n-split; wfp prefetched far above)
    short8 af[4][4];
#pragma unroll
    for (int tt = 0; tt < 4; ++tt)
#pragma unroll
        for (int kk = 0; kk < 4; ++kk)
            af[tt][kk] = ldsA(bufA, tt * 16 + lrow, kk * 32 + lgrp * 8);
    f32x4 hres[2][4];
#pragma unroll
    for (int nt = 0; nt < 2; ++nt) {
        float4 bpv = *reinterpret_cast<const float4*>(bp + cb0 + nt * 16 + lgrp * 4);
#pragma unroll
        for (int tt = 0; tt < 4; ++tt) {
            f32x4 d = {0.f, 0.f, 0.f, 0.f};
#pragma unroll
            for (int kk = 0; kk < 4; ++kk)
                d = __builtin_amdgcn_mfma_f32_16x16x32_bf16(wfp[nt][kk], af[tt][kk], d, 0, 0, 0);
            f32x4 r = hraw[nt][tt];
            r[0] += bpv.x + d[0]; r[1] += bpv.y + d[1];
            r[2] += bpv.z + d[2]; r[3] += bpv.w + d[3];
            hres[nt][tt] = r;
        }
    }

    // ---- LN2 -> xn2 in bufB
#pragma unroll
    for (int tt = 0; tt < 4; ++tt) {
        float s = 0.f, q = 0.f;
#pragma unroll
        for (int nt = 0; nt < 2; ++nt)
#pragma unroll
            for (int i = 0; i < 4; ++i) { float v = hres[nt][tt][i]; s += v; q += v * v; }
        s += __shfl_xor(s, 16, 64); s += __shfl_xor(s, 32, 64);
        q += __shfl_xor(q, 16, 64); q += __shfl_xor(q, 32, 64);
        if (lgrp == 0) { float2 t2; t2.x = s; t2.y = q; ws[wid * 64 + tt * 16 + lrow] = t2; }
    }
    bar_lds();
    short8 w1f[2][2][4];
    {
        float mu[4], rstd[4];
#pragma unroll
        for (int tt = 0; tt < 4; ++tt) {
            float s = 0.f, q = 0.f;
#pragma unroll
            for (int w = 0; w < 4; ++w) {
                float2 t2 = ws[w * 64 + tt * 16 + lrow];
                s += t2.x; q += t2.y;
            }
            float m = s * (1.f / 128.f);
            mu[tt] = m;
            rstd[tt] = rsqrtf(q * (1.f / 128.f) - m * m + 1e-5f);
        }
        float4 gv[2], bev[2];
#pragma unroll
        for (int nt = 0; nt < 2; ++nt) {
            gv[nt]  = *reinterpret_cast<const float4*>(g2 + cb0 + nt * 16 + lgrp * 4);
            bev[nt] = *reinterpret_cast<const float4*>(be2 + cb0 + nt * 16 + lgrp * 4);
        }
#pragma unroll
        for (int nt = 0; nt < 2; ++nt)
#pragma unroll
            for (int tt = 0; tt < 4; ++tt) {
                short4v pk;
                pk[0] = bfbits((hres[nt][tt][0] - mu[tt]) * rstd[tt] * gv[nt].x + bev[nt].x);
                pk[1] = bfbits((hres[nt][tt][1] - mu[tt]) * rstd[tt] * gv[nt].y + bev[nt].y);
                pk[2] = bfbits((hres[nt][tt][2] - mu[tt]) * rstd[tt] * gv[nt].z + bev[nt].z);
                pk[3] = bfbits((hres[nt][tt][3] - mu[tt]) * rstd[tt] * gv[nt].w + bev[nt].w);
                int row = tt * 16 + lrow;
                int c = cb0 + nt * 16 + lgrp * 4;
                *reinterpret_cast<short4v*>(&bufB[row * 128 + (c ^ ((row & 7) << 3))]) = pk;
            }
    }
#pragma unroll
    for (int nt = 0; nt < 2; ++nt)
#pragma unroll
        for (int kk = 0; kk < 4; ++kk)
            w1f[0][nt][kk] = gld8(w1t + (size_t)(cb0 + nt * 16 + lrow) * 128 + kk * 32 + lgrp * 8);
    bar_lds();

    // ---- MLP: 4 chunks of 128; u ping-pongs bufA/bufC; 1 barrier per chunk
    f32x4 acc2[2][4];
#pragma unroll
    for (int nt = 0; nt < 2; ++nt)
#pragma unroll
        for (int tt = 0; tt < 4; ++tt) acc2[nt][tt] = (f32x4){0.f, 0.f, 0.f, 0.f};

#pragma unroll
    for (int ch = 0; ch < 4; ++ch) {
        bf16* UB = (ch & 1) ? bufC : bufA;
        short8 w2f[2][4];
#pragma unroll
        for (int nt = 0; nt < 2; ++nt)
#pragma unroll
            for (int kk = 0; kk < 4; ++kk)
                w2f[nt][kk] = gld8(w2t + (size_t)(cb0 + nt * 16 + lrow) * 512 + ch * 128 + kk * 32 + lgrp * 8);
        float4 b1v[2];
#pragma unroll
        for (int nt = 0; nt < 2; ++nt)
            b1v[nt] = *reinterpret_cast<const float4*>(b1 + ch * 128 + cb0 + nt * 16 + lgrp * 4);
#pragma unroll
        for (int tt = 0; tt < 4; ++tt) {
            short8 xf[4];
#pragma unroll
            for (int kk = 0; kk < 4; ++kk)
                xf[kk] = ldsA(bufB, tt * 16 + lrow, kk * 32 + lgrp * 8);
#pragma unroll
            for (int nt = 0; nt < 2; ++nt) {
                f32x4 d = {0.f, 0.f, 0.f, 0.f};
#pragma unroll
                for (int kk = 0; kk < 4; ++kk)
                    d = __builtin_amdgcn_mfma_f32_16x16x32_bf16(w1f[ch & 1][nt][kk], xf[kk], d, 0, 0, 0);
                short4v pk;
                pk[0] = bfbits(gelu_fast(d[0] + b1v[nt].x)); pk[1] = bfbits(gelu_fast(d[1] + b1v[nt].y));
                pk[2] = bfbits(gelu_fast(d[2] + b1v[nt].z)); pk[3] = bfbits(gelu_fast(d[3] + b1v[nt].w));
                int row = tt * 16 + lrow;
                int c = cb0 + nt * 16 + lgrp * 4;
                *reinterpret_cast<short4v*>(&UB[row * 128 + (c ^ ((row & 7) << 3))]) = pk;
            }
        }
        if (ch < 3) {
#pragma unroll
            for (int nt = 0; nt < 2; ++nt)
#pragma unroll
                for (int kk = 0; kk < 4; ++kk)
                    w1f[(ch + 1) & 1][nt][kk] =
                        gld8(w1t + (size_t)((ch + 1) * 128 + cb0 + nt * 16 + lrow) * 128 + kk * 32 + lgrp * 8);
        }
        bar_lds();
#pragma unroll
        for (int tt = 0; tt < 4; ++tt) {
            short8 uf[4];
#pragma unroll
            for (int kk = 0; kk < 4; ++kk)
                uf[kk] = ldsA(UB, tt * 16 + lrow, kk * 32 + lgrp * 8);
#pragma unroll
            for (int nt = 0; nt < 2; ++nt)
#pragma unroll
                for (int kk = 0; kk < 4; ++kk)
                    acc2[nt][tt] = __builtin_amdgcn_mfma_f32_16x16x32_bf16(
                        w2f[nt][kk], uf[kk], acc2[nt][tt], 0, 0, 0);
        }
    }

    if (MODE == 0) {
#pragma unroll
        for (int nt = 0; nt < 2; ++nt) {
            const int n0 = cb0 + nt * 16 + lgrp * 4;
            float4 b2v = *reinterpret_cast<const float4*>(b2 + n0);
#pragma unroll
            for (int tt = 0; tt < 4; ++tt) {
                int tok = base + OFFSET + tt * 16 + lrow; if (tok >= NPIX) tok -= NPIX;
                float4 ov;
                ov.x = hres[nt][tt][0] + b2v.x + acc2[nt][tt][0];
                ov.y = hres[nt][tt][1] + b2v.y + acc2[nt][tt][1];
                ov.z = hres[nt][tt][2] + b2v.z + acc2[nt][tt][2];
                ov.w = hres[nt][tt][3] + b2v.w + acc2[nt][tt][3];
                *reinterpret_cast<float4*>(h + (size_t)tok * 128 + n0) = ov;
            }
        }
    } else {
        short8 wff[4];
#pragma unroll
        for (int kk = 0; kk < 4; ++kk)
            wff[kk] = gld8(wf2t + (size_t)(wid * 16 + lrow) * 128 + kk * 32 + lgrp * 8);
        float4 xv[4];
#pragma unroll
        for (int tt = 0; tt < 4; ++tt) {
            int tok = base + OFFSET + tt * 16 + lrow; if (tok >= NPIX) tok -= NPIX;
            xv[tt] = *reinterpret_cast<const float4*>(x + (size_t)tok * 64 + wid * 16 + lgrp * 4);
        }
        bar_lds();   // mlp2 u-reads done before bufB overwrite
#pragma unroll
        for (int nt = 0; nt < 2; ++nt) {
            const int n0 = cb0 + nt * 16 + lgrp * 4;
            float4 b2v = *reinterpret_cast<const float4*>(b2 + n0);
#pragma unroll
            for (int tt = 0; tt < 4; ++tt) {
                short4v pk;
                pk[0] = bfbits(hres[nt][tt][0] + b2v.x + acc2[nt][tt][0]);
                pk[1] = bfbits(hres[nt][tt][1] + b2v.y + acc2[nt][tt][1]);
                pk[2] = bfbits(hres[nt][tt][2] + b2v.z + acc2[nt][tt][2]);
                pk[3] = bfbits(hres[nt][tt][3] + b2v.w + acc2[nt][tt][3]);
                int row = tt * 16 + lrow;
                int c = cb0 + nt * 16 + lgrp * 4;
                *reinterpret_cast<short4v*>(&bufB[row * 128 + (c ^ ((row & 7) << 3))]) = pk;
            }
        }
        bar_lds();
        float4 bfv = *reinterpret_cast<const float4*>(bf2 + wid * 16 + lgrp * 4);
#pragma unroll
        for (int tt = 0; tt < 4; ++tt) {
            short8 bfr[4];
#pragma unroll
            for (int kk = 0; kk < 4; ++kk)
                bfr[kk] = ldsA(bufB, tt * 16 + lrow, kk * 32 + lgrp * 8);
            f32x4 d = {0.f, 0.f, 0.f, 0.f};
#pragma unroll
            for (int kk = 0; kk < 4; ++kk)
                d = __builtin_amdgcn_mfma_f32_16x16x32_bf16(wff[kk], bfr[kk], d, 0, 0, 0);
            int tok = base + OFFSET + tt * 16 + lrow; if (tok >= NPIX) tok -= NPIX;
            float4 ov;
            ov.x = xv[tt].x + bfv.x + d[0]; ov.y = xv[tt].y + bfv.y + d[1];
            ov.z = xv[tt].z + bfv.z + d[2]; ov.w = xv[tt].w + bfv.w + d[3];
            *reinterpret_cast<float4*>(out + (size_t)tok * 64 + wid * 16 + lgrp * 4) = ov;
        }
    }
}

extern "C" void kernel_launch(void* const* d_in, const int* in_sizes, int n_in,
                              void* d_out, int out_size, void* d_ws, size_t ws_size,
                              hipStream_t stream) {
    (void)in_sizes; (void)n_in; (void)out_size; (void)ws_size;
    const float* x      = (const float*)d_in[0];
    const float* w_ff1  = (const float*)d_in[1];
    const float* b_ff1  = (const float*)d_in[2];
    const float* ln1_g  = (const float*)d_in[3];
    const float* ln1_b  = (const float*)d_in[4];
    const float* w_qkv  = (const float*)d_in[5];
    const float* b_qkv  = (const float*)d_in[6];
    const float* w_proj = (const float*)d_in[7];
    const float* b_proj = (const float*)d_in[8];
    const float* ln2_g  = (const float*)d_in[9];
    const float* ln2_b  = (const float*)d_in[10];
    const float* w_mlp1 = (const float*)d_in[11];
    const float* b_mlp1 = (const float*)d_in[12];
    const float* w_mlp2 = (const float*)d_in[13];
    const float* b_mlp2 = (const float*)d_in[14];
    const float* w_ff2  = (const float*)d_in[15];
    const float* b_ff2  = (const float*)d_in[16];
    float* out = (float*)d_out;

    float* h = (float*)d_ws;                                   // [NPIX,128] fp32
    bf16* wbf = (bf16*)((char*)d_ws + (size_t)NPIX * 128 * 4);
    bf16* ff1t  = wbf;            // [128][64]
    bf16* qkvt  = wbf + 8192;     // 2x[384][128]
    bf16* projt = wbf + 106496;   // 2x[128][128]
    bf16* mlp1t = wbf + 139264;   // 2x[512][128]
    bf16* mlp2t = wbf + 270336;   // 2x[128][512]
    bf16* ff2t  = wbf + 401408;   // [64][128]

    k_convert<<<1600, dim3(256), 0, stream>>>(w_ff1, w_qkv, w_proj, w_mlp1, w_mlp2, w_ff2, wbf);

    const int NB = NPIX / 64;  // 3072
    k_block<0, 0><<<NB, dim3(256), 0, stream>>>(x, h,
        ff1t, b_ff1,
        ln1_g, ln1_b, qkvt, b_qkv, projt, b_proj,
        ln2_g, ln2_b, mlp1t, b_mlp1, mlp2t, b_mlp2,
        ff2t, b_ff2, out);

    k_block<8, 1><<<NB, dim3(256), 0, stream>>>(x, h,
        ff1t, b_ff1,
        ln1_g + 128, ln1_b + 128, qkvt + 49152, b_qkv + 384, projt + 16384, b_proj + 128,
        ln2_g + 128, ln2_b + 128, mlp1t + 65536, b_mlp1 + 512, mlp2t + 65536, b_mlp2 + 128,
        ff2t, b_ff2, out);
}